// Round 4
// baseline (304.626 us; speedup 1.0000x reference)
//
#include <hip/hip_runtime.h>
#include <hip/hip_bf16.h>
#include <math.h>

typedef __bf16 bf16_t;
typedef __bf16 bf16x8 __attribute__((ext_vector_type(8)));
typedef __bf16 bf16x4 __attribute__((ext_vector_type(4)));
typedef float  f32x4  __attribute__((ext_vector_type(4)));

#define L_DIM 2048
#define D_DIM 1024
#define H_DIM 16
#define M_DIM 4096
#define KTOP 409
#define SLOTS 448    // 7 * 64, padded (sel = -1 beyond KTOP)
#define KSPLIT 8
#define KCHUNK 256   // L_DIM / KSPLIT
#define HSZ (L_DIM * 64)   // elements per (b,h) head block = 131072

// split f32 into bf16 hi + bf16 lo (a ~= hi + lo)
__device__ __forceinline__ void split2(float a, bf16_t& h, bf16_t& l) {
  h = (bf16_t)a;
  l = (bf16_t)(a - (float)h);
}

// async global -> LDS, 16B per lane; lds ptr must be wave-uniform (m104/m108)
__device__ __forceinline__ void gld16(const bf16_t* g, bf16_t* l) {
  __builtin_amdgcn_global_load_lds(
      (const __attribute__((address_space(1))) void*)g,
      (__attribute__((address_space(3))) void*)l, 16, 0, 0);
}

// stage a 128x32 bf16 tile (row stride D_DIM) into unpadded LDS.
// wave w covers segments {2w, 2w+1}; seg s = rows 16s..16s+15.
#define STAGE_TILE128(src, dst)                                               \
  {                                                                           \
    const int seg0 = wave * 2;                                                \
    const int r0 = seg0 * 16 + (lane >> 2);                                   \
    const int c0 = (lane & 3) * 8;                                            \
    gld16((src) + (size_t)r0 * D_DIM + c0, (dst) + seg0 * 512);               \
    gld16((src) + (size_t)(r0 + 16) * D_DIM + c0, (dst) + (seg0 + 1) * 512);  \
  }

// stage a 64x32 bf16 tile: one 16-row segment per wave.
#define STAGE_TILE64(src, dst)                                                \
  {                                                                           \
    const int r0 = wave * 16 + (lane >> 2);                                   \
    const int c0 = (lane & 3) * 8;                                            \
    gld16((src) + (size_t)r0 * D_DIM + c0, (dst) + wave * 512);               \
  }

// ---------------------------------------------------------------------------
// prep: pre-split x and Wq into bf16 hi/lo; pre-round Wk/Wv/Wo to bf16.
// ---------------------------------------------------------------------------
__global__ __launch_bounds__(256) void prep_kernel(
    const float* __restrict__ x,  const float* __restrict__ Wq,
    const float* __restrict__ Wk, const float* __restrict__ Wv,
    const float* __restrict__ Wo,
    bf16_t* __restrict__ xhi, bf16_t* __restrict__ xlo,
    bf16_t* __restrict__ Wqhi, bf16_t* __restrict__ Wqlo,
    bf16_t* __restrict__ Wkb,  bf16_t* __restrict__ Wvb,
    bf16_t* __restrict__ Wob)
{
  const int XV = (M_DIM * D_DIM) / 4;
  const int WV = (D_DIM * D_DIM) / 4;
  int i = blockIdx.x * 256 + threadIdx.x;
  if (i < XV) {
    f32x4 v = ((const f32x4*)x)[i];
    bf16x4 h, l;
    #pragma unroll
    for (int j = 0; j < 4; ++j) { bf16_t hh, ll; split2(v[j], hh, ll); h[j] = hh; l[j] = ll; }
    ((bf16x4*)xhi)[i] = h;
    ((bf16x4*)xlo)[i] = l;
  } else if (i < XV + WV) {
    int j0 = i - XV;
    f32x4 v = ((const f32x4*)Wq)[j0];
    bf16x4 h, l;
    #pragma unroll
    for (int j = 0; j < 4; ++j) { bf16_t hh, ll; split2(v[j], hh, ll); h[j] = hh; l[j] = ll; }
    ((bf16x4*)Wqhi)[j0] = h;
    ((bf16x4*)Wqlo)[j0] = l;
  } else if (i < XV + 2 * WV) {
    int j0 = i - XV - WV;
    f32x4 v = ((const f32x4*)Wk)[j0];
    bf16x4 h;
    #pragma unroll
    for (int j = 0; j < 4; ++j) h[j] = (bf16_t)v[j];
    ((bf16x4*)Wkb)[j0] = h;
  } else if (i < XV + 3 * WV) {
    int j0 = i - XV - 2 * WV;
    f32x4 v = ((const f32x4*)Wv)[j0];
    bf16x4 h;
    #pragma unroll
    for (int j = 0; j < 4; ++j) h[j] = (bf16_t)v[j];
    ((bf16x4*)Wvb)[j0] = h;
  } else {
    int j0 = i - XV - 3 * WV;
    f32x4 v = ((const f32x4*)Wo)[j0];
    bf16x4 h;
    #pragma unroll
    for (int j = 0; j < 4; ++j) h[j] = (bf16_t)v[j];
    ((bf16x4*)Wob)[j0] = h;
  }
}

// ---------------------------------------------------------------------------
// Fused QKV projections, prefetch double-buffered staging.
// Round-4 z0: MERGED single-pass 3-product — stage {xh, xl, Wqh, Wql} per
// K-step (64KB LDS, 2 blocks/CU), 48 MFMA/step, 32 steps: halves barrier
// drains vs the A/B phase split and avoids re-staging Wqh.
// K written per-head [b][h][L][64]; V per-head key-tiled [(b,h)][kb][d][32].
// ---------------------------------------------------------------------------
__global__ __launch_bounds__(256, 2) void gemm_qkv(
    const bf16_t* __restrict__ xhi, const bf16_t* __restrict__ xlo,
    const bf16_t* __restrict__ Wqhi, const bf16_t* __restrict__ Wqlo,
    const bf16_t* __restrict__ Wkb, const bf16_t* __restrict__ Wvb,
    const float* __restrict__ bq, const float* __restrict__ bk, const float* __restrict__ bv,
    bf16_t* __restrict__ Qhi, bf16_t* __restrict__ Khi, bf16_t* __restrict__ VThi,
    float* __restrict__ norms)
{
  const int bx = blockIdx.x;
  const int z  = bx % 3;          // interleaved so each CU gets a z-mix
  const int id = bx / 3;          // 0..255
  const int n0   = (id & 7) * 128;
  const int row0 = (id >> 3) * 128;

  __shared__ __align__(16) bf16_t sm[2][4][4096];   // 64 KB: dbuf x 4 tiles

  const int tid  = threadIdx.x;
  const int lane = tid & 63;
  const int wave = tid >> 6;
  const int wr = wave >> 1, wc = wave & 1;
  const int lm = lane & 15, quad = lane >> 4;

  const f32x4 vzero = {0.f, 0.f, 0.f, 0.f};
  f32x4 acc[4][4];
  #pragma unroll
  for (int mi = 0; mi < 4; ++mi)
    #pragma unroll
    for (int ni = 0; ni < 4; ++ni) acc[mi][ni] = vzero;

  if (z == 0) {
#define STAGE_M(k0, b) do {                                                  \
      STAGE_TILE128(xhi  + (size_t)row0 * D_DIM + (k0), sm[b][0]);           \
      STAGE_TILE128(xlo  + (size_t)row0 * D_DIM + (k0), sm[b][1]);           \
      STAGE_TILE128(Wqhi + (size_t)n0   * D_DIM + (k0), sm[b][2]);           \
      STAGE_TILE128(Wqlo + (size_t)n0   * D_DIM + (k0), sm[b][3]);           \
    } while (0)

    STAGE_M(0, 0);
    __syncthreads();
    int cur = 0;
    for (int k0 = 0; k0 < D_DIM; k0 += 32) {
      if (k0 + 32 < D_DIM) STAGE_M(k0 + 32, cur ^ 1);
      bf16x8 afh[4], afl[4], bh0[4], bl0[4];
      #pragma unroll
      for (int mi = 0; mi < 4; ++mi) {
        afh[mi] = *reinterpret_cast<const bf16x8*>(&sm[cur][0][(wr * 64 + mi * 16 + lm) * 32 + quad * 8]);
        afl[mi] = *reinterpret_cast<const bf16x8*>(&sm[cur][1][(wr * 64 + mi * 16 + lm) * 32 + quad * 8]);
      }
      #pragma unroll
      for (int ni = 0; ni < 4; ++ni) {
        bh0[ni] = *reinterpret_cast<const bf16x8*>(&sm[cur][2][(wc * 64 + ni * 16 + lm) * 32 + quad * 8]);
        bl0[ni] = *reinterpret_cast<const bf16x8*>(&sm[cur][3][(wc * 64 + ni * 16 + lm) * 32 + quad * 8]);
      }
      #pragma unroll
      for (int mi = 0; mi < 4; ++mi)
        #pragma unroll
        for (int ni = 0; ni < 4; ++ni) {
          acc[mi][ni] = __builtin_amdgcn_mfma_f32_16x16x32_bf16(afh[mi], bh0[ni], acc[mi][ni], 0, 0, 0);
          acc[mi][ni] = __builtin_amdgcn_mfma_f32_16x16x32_bf16(afh[mi], bl0[ni], acc[mi][ni], 0, 0, 0);
          acc[mi][ni] = __builtin_amdgcn_mfma_f32_16x16x32_bf16(afl[mi], bh0[ni], acc[mi][ni], 0, 0, 0);
        }
      __syncthreads();
      cur ^= 1;
    }

    float bvv[4];
    #pragma unroll
    for (int ni = 0; ni < 4; ++ni) bvv[ni] = bq[n0 + wc * 64 + ni * 16 + lm];
    #pragma unroll
    for (int mi = 0; mi < 4; ++mi)
      #pragma unroll
      for (int ni = 0; ni < 4; ++ni)
        #pragma unroll
        for (int r = 0; r < 4; ++r) acc[mi][ni][r] += bvv[ni];

    const int h = (n0 + wc * 64) >> 6;
    #pragma unroll
    for (int mi = 0; mi < 4; ++mi)
      #pragma unroll
      for (int r = 0; r < 4; ++r) {
        float s = 0.f;
        #pragma unroll
        for (int ni = 0; ni < 4; ++ni) { float v = acc[mi][ni][r]; s += v * v; }
        s += __shfl_xor(s, 1); s += __shfl_xor(s, 2);
        s += __shfl_xor(s, 4); s += __shfl_xor(s, 8);
        if (lm == 0) {
          int row = row0 + wr * 64 + mi * 16 + quad * 4 + r;
          int bb = row >> 11, ll = row & (L_DIM - 1);
          norms[(bb * H_DIM + h) * L_DIM + ll] = s;
        }
      }

    #pragma unroll
    for (int mi = 0; mi < 4; ++mi)
      #pragma unroll
      for (int r = 0; r < 4; ++r) {
        int row = row0 + wr * 64 + mi * 16 + quad * 4 + r;
        #pragma unroll
        for (int ni = 0; ni < 4; ++ni)
          Qhi[(size_t)row * D_DIM + n0 + wc * 64 + ni * 16 + lm] = (bf16_t)acc[mi][ni][r];
      }
  } else {
    const bf16_t* W = (z == 1) ? Wkb : Wvb;
#define STAGE_L(k0, b) do {                                                  \
      STAGE_TILE128(xhi + (size_t)row0 * D_DIM + (k0), sm[b][0]);            \
      STAGE_TILE128(W   + (size_t)n0   * D_DIM + (k0), sm[b][1]);            \
    } while (0)

    STAGE_L(0, 0);
    __syncthreads();
    int cur = 0;
    for (int k0 = 0; k0 < D_DIM; k0 += 32) {
      if (k0 + 32 < D_DIM) STAGE_L(k0 + 32, cur ^ 1);
      bf16x8 af[4], bfr[4];
      #pragma unroll
      for (int mi = 0; mi < 4; ++mi)
        af[mi] = *reinterpret_cast<const bf16x8*>(&sm[cur][0][(wr * 64 + mi * 16 + lm) * 32 + quad * 8]);
      #pragma unroll
      for (int ni = 0; ni < 4; ++ni)
        bfr[ni] = *reinterpret_cast<const bf16x8*>(&sm[cur][1][(wc * 64 + ni * 16 + lm) * 32 + quad * 8]);
      #pragma unroll
      for (int mi = 0; mi < 4; ++mi)
        #pragma unroll
        for (int ni = 0; ni < 4; ++ni)
          acc[mi][ni] = __builtin_amdgcn_mfma_f32_16x16x32_bf16(af[mi], bfr[ni], acc[mi][ni], 0, 0, 0);
      __syncthreads();
      cur ^= 1;
    }

    const float* bias = (z == 1) ? bk : bv;
    float bvv[4];
    #pragma unroll
    for (int ni = 0; ni < 4; ++ni) bvv[ni] = bias[n0 + wc * 64 + ni * 16 + lm];
    #pragma unroll
    for (int mi = 0; mi < 4; ++mi)
      #pragma unroll
      for (int ni = 0; ni < 4; ++ni)
        #pragma unroll
        for (int r = 0; r < 4; ++r) acc[mi][ni][r] += bvv[ni];

    const int hh = (n0 + wc * 64) >> 6;   // head 0..15
    if (z == 1) {
      // Khead[b][h][l][64]
      #pragma unroll
      for (int mi = 0; mi < 4; ++mi)
        #pragma unroll
        for (int r = 0; r < 4; ++r) {
          int row = row0 + wr * 64 + mi * 16 + quad * 4 + r;
          int bb = row >> 11, ll = row & (L_DIM - 1);
          size_t base = (size_t)(bb * H_DIM + hh) * HSZ + (size_t)ll * 64;
          #pragma unroll
          for (int ni = 0; ni < 4; ++ni)
            Khi[base + ni * 16 + lm] = (bf16_t)acc[mi][ni][r];
        }
    } else {
      // V key-tiled: [(b,h)][kb=l/32][d][32]
      #pragma unroll
      for (int mi = 0; mi < 4; ++mi) {
        int rbase = row0 + wr * 64 + mi * 16 + quad * 4;
        int bb = rbase >> 11, l0 = rbase & (L_DIM - 1);
        int kbv = l0 >> 5, kin = l0 & 31;
        size_t hb = (size_t)(bb * H_DIM + hh) * HSZ;
        #pragma unroll
        for (int ni = 0; ni < 4; ++ni) {
          int d = ni * 16 + lm;
          bf16x4 wv;
          #pragma unroll
          for (int r = 0; r < 4; ++r) wv[r] = (bf16_t)acc[mi][ni][r];
          *reinterpret_cast<bf16x4*>(&VThi[hb + (size_t)(kbv * 64 + d) * 32 + kin]) = wv;
        }
      }
    }
  }
}

// ---------------------------------------------------------------------------
// Output projection: 64x128 tiles, grid (8,64) = 2 blocks/CU, prefetch dbuf.
// ---------------------------------------------------------------------------
__global__ __launch_bounds__(256) void gemm_out(
    const bf16_t* __restrict__ Ahi, const bf16_t* __restrict__ Wob,
    const float* __restrict__ bias, float* __restrict__ C)
{
  const int n0   = blockIdx.x * 128;
  const int row0 = blockIdx.y * 64;

  __shared__ __align__(16) bf16_t sm[2][6144];   // 24 KB: dbuf x (A64 + B128)

  const int tid  = threadIdx.x;
  const int lane = tid & 63;
  const int wave = tid >> 6;
  const int wr = wave >> 1, wc = wave & 1;
  const int lm = lane & 15, quad = lane >> 4;

  const f32x4 vzero = {0.f, 0.f, 0.f, 0.f};
  f32x4 acc[2][4];
  #pragma unroll
  for (int mi = 0; mi < 2; ++mi)
    #pragma unroll
    for (int ni = 0; ni < 4; ++ni) acc[mi][ni] = vzero;

#define STAGE_O(k0, b) do {                                                  \
    STAGE_TILE64(Ahi + (size_t)row0 * D_DIM + (k0), sm[b]);                  \
    STAGE_TILE128(Wob + (size_t)n0 * D_DIM + (k0), sm[b] + 2048);            \
  } while (0)

  STAGE_O(0, 0);
  __syncthreads();
  int cur = 0;
  for (int k0 = 0; k0 < D_DIM; k0 += 32) {
    if (k0 + 32 < D_DIM) STAGE_O(k0 + 32, cur ^ 1);
    bf16x8 af[2], bfr[4];
    #pragma unroll
    for (int mi = 0; mi < 2; ++mi)
      af[mi] = *reinterpret_cast<const bf16x8*>(&sm[cur][(wr * 32 + mi * 16 + lm) * 32 + quad * 8]);
    #pragma unroll
    for (int ni = 0; ni < 4; ++ni)
      bfr[ni] = *reinterpret_cast<const bf16x8*>(&sm[cur][2048 + (wc * 64 + ni * 16 + lm) * 32 + quad * 8]);
    #pragma unroll
    for (int mi = 0; mi < 2; ++mi)
      #pragma unroll
      for (int ni = 0; ni < 4; ++ni)
        acc[mi][ni] = __builtin_amdgcn_mfma_f32_16x16x32_bf16(af[mi], bfr[ni], acc[mi][ni], 0, 0, 0);
    __syncthreads();
    cur ^= 1;
  }

  float bvv[4];
  #pragma unroll
  for (int ni = 0; ni < 4; ++ni) bvv[ni] = bias[n0 + wc * 64 + ni * 16 + lm];
  #pragma unroll
  for (int mi = 0; mi < 2; ++mi)
    #pragma unroll
    for (int r = 0; r < 4; ++r) {
      int row = row0 + wr * 32 + mi * 16 + quad * 4 + r;
      #pragma unroll
      for (int ni = 0; ni < 4; ++ni)
        C[(size_t)row * D_DIM + n0 + wc * 64 + ni * 16 + lm] = acc[mi][ni][r] + bvv[ni];
    }
}

// ---------------------------------------------------------------------------
// Exact top-409 per (b,h): bitonic sort (norm desc, idx asc) = lax.top_k set.
// Also writes rowmap[bh][l] = slot (or -1) for the fused fill kernel.
// ---------------------------------------------------------------------------
__global__ __launch_bounds__(1024) void topk_kernel(
    const float* __restrict__ norms, int* __restrict__ sel,
    int* __restrict__ rowmap)
{
  const int bh = blockIdx.x;
  __shared__ __align__(16) float val[L_DIM];
  __shared__ __align__(16) int   idx[L_DIM];
  const int t = threadIdx.x;
  for (int i = t; i < L_DIM; i += 1024) {
    val[i] = norms[bh * L_DIM + i];
    idx[i] = i;
    rowmap[bh * L_DIM + i] = -1;
  }
  __syncthreads();
  for (int k = 2; k <= L_DIM; k <<= 1) {
    for (int j = k >> 1; j > 0; j >>= 1) {
      for (int i = t; i < L_DIM; i += 1024) {
        int ixj = i ^ j;
        if (ixj > i) {
          float v1 = val[i], v2 = val[ixj];
          int   i1 = idx[i], i2 = idx[ixj];
          bool up = ((i & k) == 0);
          bool sw = up ? ((v2 > v1) || (v2 == v1 && i2 < i1))
                       : ((v1 > v2) || (v1 == v2 && i1 < i2));
          if (sw) { val[i] = v2; val[ixj] = v1; idx[i] = i2; idx[ixj] = i1; }
        }
      }
      __syncthreads();
    }
  }
  for (int i = t; i < SLOTS; i += 1024)
    sel[bh * SLOTS + i] = (i < KTOP) ? idx[i] : -1;
  if (t < KTOP)  // KTOP=409 < 1024: one pass
    rowmap[bh * L_DIM + idx[t]] = t;
}

// ---------------------------------------------------------------------------
// K-split flash attention. K per-head [b][h][L][64]; V key-tiled
// [(b,h)][kb][d][32]. XCD-affinity block swizzle; 2x-unrolled inner loop
// with double-buffered P.
// ---------------------------------------------------------------------------
__global__ __launch_bounds__(256) void attn_kernel(
    const bf16_t* __restrict__ Qhi,
    const bf16_t* __restrict__ Khi,
    const bf16_t* __restrict__ VThi,
    const int* __restrict__ sel,
    float* __restrict__ Ol, bf16_t* __restrict__ Oo)
{
  const int bx = blockIdx.x;
  const int xl = bx & 7;          // XCD id under default round-robin
  const int rest = bx >> 3;       // 0..223
  const int qc = rest % 7;
  const int gh = rest / 7;        // 0..31
  const int g  = gh * 8 + xl;     // K/V-chunk group 0..255
  const int bh = g & 31;
  const int ks = g >> 5;
  const int b = bh >> 4, h = bh & 15;
  const int wave = threadIdx.x >> 6;
  const int lane = threadIdx.x & 63;
  const int lm = lane & 15, quad = lane >> 4;

  __shared__ __align__(16) bf16_t sPh[2][4][16][40];

  const int qbase = qc * 64 + wave * 16;
  const int qi = sel[bh * SLOTS + qbase + lm];
  const size_t qo = ((size_t)(b * L_DIM + (qi >= 0 ? qi : 0))) * D_DIM + h * 64;
  const bf16x8 qa0 = *reinterpret_cast<const bf16x8*>(&Qhi[qo + quad * 8]);
  const bf16x8 qa1 = *reinterpret_cast<const bf16x8*>(&Qhi[qo + 32 + quad * 8]);

  const f32x4 vzero = {0.f, 0.f, 0.f, 0.f};
  float l_l[4] = {0.f, 0.f, 0.f, 0.f};
  f32x4 o[4];
  #pragma unroll
  for (int ni = 0; ni < 4; ++ni) o[ni] = vzero;

  const float scale = 0.125f;
  const size_t khead = (size_t)(b * H_DIM + h) * HSZ;
  const int key0 = ks * KCHUNK;

  // inner name 'kof' differs from the caller's loop var (r2 self-shadow UB)
#define ATTN_STEP(KT, PB)                                                     \
  {                                                                           \
    const int kof = (KT);                                                     \
    size_t kr0 = khead + (size_t)(key0 + kof + lm) * 64;                      \
    size_t kr1 = khead + (size_t)(key0 + kof + 16 + lm) * 64;                 \
    bf16x8 kb0 = *reinterpret_cast<const bf16x8*>(&Khi[kr0 + quad * 8]);      \
    bf16x8 kb1 = *reinterpret_cast<const bf16x8*>(&Khi[kr0 + 32 + quad * 8]); \
    bf16x8 kb2 = *reinterpret_cast<const bf16x8*>(&Khi[kr1 + quad * 8]);      \
    bf16x8 kb3 = *reinterpret_cast<const bf16x8*>(&Khi[kr1 + 32 + quad * 8]); \
    const int kbv = (key0 + kof) >> 5;                                        \
    bf16x8 vbh[4];                                                            \
    _Pragma("unroll")                                                         \
    for (int ni = 0; ni < 4; ++ni) {                                          \
      size_t vo = khead + (size_t)(kbv * 64 + ni * 16 + lm) * 32 + quad * 8;  \
      vbh[ni] = *reinterpret_cast<const bf16x8*>(&VThi[vo]);                  \
    }                                                                         \
    f32x4 s0 = vzero, s1 = vzero;                                             \
    s0 = __builtin_amdgcn_mfma_f32_16x16x32_bf16(qa0, kb0, s0, 0, 0, 0);      \
    s0 = __builtin_amdgcn_mfma_f32_16x16x32_bf16(qa1, kb1, s0, 0, 0, 0);      \
    s1 = __builtin_amdgcn_mfma_f32_16x16x32_bf16(qa0, kb2, s1, 0, 0, 0);      \
    s1 = __builtin_amdgcn_mfma_f32_16x16x32_bf16(qa1, kb3, s1, 0, 0, 0);      \
    _Pragma("unroll")                                                         \
    for (int r = 0; r < 4; ++r) {                                             \
      float p0 = __expf(s0[r] * scale);                                       \
      float p1 = __expf(s1[r] * scale);                                       \
      l_l[r] += p0 + p1;                                                      \
      sPh[PB][wave][quad * 4 + r][lm]      = (bf16_t)p0;                      \
      sPh[PB][wave][quad * 4 + r][16 + lm] = (bf16_t)p1;                      \
    }                                                                         \
    bf16x8 pah = *reinterpret_cast<const bf16x8*>(&sPh[PB][wave][lm][quad * 8]); \
    _Pragma("unroll")                                                         \
    for (int ni = 0; ni < 4; ++ni)                                            \
      o[ni] = __builtin_amdgcn_mfma_f32_16x16x32_bf16(pah, vbh[ni], o[ni], 0, 0, 0); \
  }

  for (int kt = 0; kt < KCHUNK; kt += 64) {
    ATTN_STEP(kt, 0);
    ATTN_STEP(kt + 32, 1);
  }

  #pragma unroll
  for (int r = 0; r < 4; ++r) {
    l_l[r] += __shfl_xor(l_l[r], 1);
    l_l[r] += __shfl_xor(l_l[r], 2);
    l_l[r] += __shfl_xor(l_l[r], 4);
    l_l[r] += __shfl_xor(l_l[r], 8);
  }

  #pragma unroll
  for (int r = 0; r < 4; ++r) {
    int slot = qbase + quad * 4 + r;
    int s2 = sel[bh * SLOTS + slot];
    if (s2 >= 0) {
      size_t gs = (size_t)(bh * SLOTS + slot) * KSPLIT + ks;
      if (lm == 0) Ol[gs] = l_l[r];
      #pragma unroll
      for (int ni = 0; ni < 4; ++ni)
        Oo[gs * 64 + ni * 16 + lm] = (bf16_t)o[ni][r];
    }
  }
}

// ---------------------------------------------------------------------------
// Fused fill: mean(V) for non-selected rows, ksplit-combine for selected.
// Each AO row written exactly once. Wave-uniform branch (rowmap per row).
// ---------------------------------------------------------------------------
__global__ __launch_bounds__(256) void fill_kernel(
    const float* __restrict__ Ol, const bf16_t* __restrict__ Oo,
    const int* __restrict__ rowmap, const bf16_t* __restrict__ VThi,
    bf16_t* __restrict__ AOhi)
{
  const int bh = blockIdx.x;
  const int b = bh >> 4, h = bh & 15;
  const int t = threadIdx.x;
  __shared__ __align__(16) bf16_t smh[64];
  {
    const int hd = t >> 2, part = t & 3;
    size_t hbase = (size_t)(b * H_DIM + h) * HSZ;
    float s = 0.f;
    for (int kb = part * 16; kb < part * 16 + 16; ++kb) {
      size_t a = hbase + (size_t)(kb * 64 + hd) * 32;
      bf16x8 v0 = *reinterpret_cast<const bf16x8*>(&VThi[a]);
      bf16x8 v1 = *reinterpret_cast<const bf16x8*>(&VThi[a + 8]);
      bf16x8 v2 = *reinterpret_cast<const bf16x8*>(&VThi[a + 16]);
      bf16x8 v3 = *reinterpret_cast<const bf16x8*>(&VThi[a + 24]);
      #pragma unroll
      for (int j = 0; j < 8; ++j)
        s += (float)v0[j] + (float)v1[j] + (float)v2[j] + (float)v3[j];
    }
    s += __shfl_xor(s, 1);
    s += __shfl_xor(s, 2);
    if (part == 0) smh[hd] = (bf16_t)(s * (1.0f / (float)L_DIM));
  }
  __syncthreads();

  const int lane = t & 63;
  const int w = t >> 6;
  const int lbase = blockIdx.y * 256 + w * 64;
  for (int j = 0; j < 64; ++j) {
    int l = lbase + j;
    int s = rowmap[bh * L_DIM + l];   // wave-uniform
    bf16_t outv;
    if (s < 0) {
      outv = smh[lane];
    } else {
      size_t gs = ((size_t)(bh * SLOTS + s)) * KSPLIT;
      float L = 0.f, ov = 0.f;
      #pragma unroll
      for (int sp = 0; sp < KSPLIT; ++sp) {
        L  += Ol[gs + sp];
        ov += (float)Oo[(gs + sp) * 64 + lane];
      }
      outv = (bf16_t)(ov / L);
    }
    AOhi[((size_t)(b * L_DIM + l)) * D_DIM + h * 64 + lane] = outv;
  }
}

// ---------------------------------------------------------------------------
extern "C" void kernel_launch(void* const* d_in, const int* in_sizes, int n_in,
                              void* d_out, int out_size, void* d_ws, size_t ws_size,
                              hipStream_t stream) {
  const float* x  = (const float*)d_in[0];
  const float* Wq = (const float*)d_in[1];
  const float* bq = (const float*)d_in[2];
  const float* Wk = (const float*)d_in[3];
  const float* bk = (const float*)d_in[4];
  const float* Wv = (const float*)d_in[5];
  const float* bv = (const float*)d_in[6];
  const float* Wo = (const float*)d_in[7];
  const float* bo = (const float*)d_in[8];
  float* out = (float*)d_out;

  // ws layout (~43 MB):
  //  [0,8)    Qhi  (aliased as AOhi after attn)
  //  [8,16)   VThi (key-tiled per-head layout)
  //  [16,24)  xhi  -+ dead after gemm_qkv; [16,~30.7) reused for Oo
  //  [24,32)  xlo  -+  [31,32) rowmap (written by topk, after xlo is dead)
  //  [32,34)  Wqhi  [34,36) Wqlo  [36,38) Wkb  [38,40) Wvb  [40,42) Wob
  //  [42,..)  norms (256 KB), sel (57 KB), Ol (458 KB)
  // Khi (per-head layout) lives in d_out (8 of 16 MB) — dead until gemm_out.
  const size_t MB = 1u << 20;
  char* ws = (char*)d_ws;
  bf16_t* Qhi  = (bf16_t*)(ws);
  bf16_t* VThi = (bf16_t*)(ws + 8 * MB);
  bf16_t* xhi  = (bf16_t*)(ws + 16 * MB);
  bf16_t* xlo  = (bf16_t*)(ws + 24 * MB);
  bf16_t* Oo   = (bf16_t*)(ws + 16 * MB);         // aliases xhi/xlo, 14.7MB
  int*    rowmap = (int*)(ws + 31 * MB);          // 256 KB, after Oo's tail
  bf16_t* Wqhi = (bf16_t*)(ws + 32 * MB);
  bf16_t* Wqlo = (bf16_t*)(ws + 34 * MB);
  bf16_t* Wkb  = (bf16_t*)(ws + 36 * MB);
  bf16_t* Wvb  = (bf16_t*)(ws + 38 * MB);
  bf16_t* Wob  = (bf16_t*)(ws + 40 * MB);
  float*  norms = (float*)(ws + 42 * MB);
  int*    sel   = (int*)(ws + 42 * MB + (256u << 10));
  float*  Ol    = (float*)(ws + 42 * MB + (320u << 10));
  bf16_t* AOhi = Qhi;
  bf16_t* Khi = (bf16_t*)d_out;

  dim3 blk(256);
  prep_kernel<<<dim3(8192), blk, 0, stream>>>(x, Wq, Wk, Wv, Wo,
                                              xhi, xlo, Wqhi, Wqlo, Wkb, Wvb, Wob);
  gemm_qkv<<<dim3(768), blk, 0, stream>>>(xhi, xlo, Wqhi, Wqlo, Wkb, Wvb,
                                          bq, bk, bv, Qhi, Khi, VThi, norms);
  topk_kernel<<<dim3(32), dim3(1024), 0, stream>>>(norms, sel, rowmap);
  attn_kernel<<<dim3(32 * 7 * KSPLIT), blk, 0, stream>>>(Qhi, Khi, VThi, sel, Ol, Oo);
  fill_kernel<<<dim3(32, 8), blk, 0, stream>>>(Ol, Oo, rowmap, VThi, AOhi);
  gemm_out<<<dim3(8, 64), blk, 0, stream>>>(AOhi, Wob, bo, out);
}

// Round 5
// 268.384 us; speedup vs baseline: 1.1350x; 1.1350x over previous
//
#include <hip/hip_runtime.h>
#include <hip/hip_bf16.h>
#include <math.h>

typedef __bf16 bf16_t;
typedef __bf16 bf16x8 __attribute__((ext_vector_type(8)));
typedef __bf16 bf16x4 __attribute__((ext_vector_type(4)));
typedef float  f32x4  __attribute__((ext_vector_type(4)));

#define L_DIM 2048
#define D_DIM 1024
#define H_DIM 16
#define M_DIM 4096
#define KTOP 409
#define SLOTS 448    // 7 * 64, padded (sel = -1 beyond KTOP)
#define KSPLIT 8
#define KCHUNK 256   // L_DIM / KSPLIT
#define HSZ (L_DIM * 64)   // elements per (b,h) head block = 131072

// split f32 into bf16 hi + bf16 lo (a ~= hi + lo)
__device__ __forceinline__ void split2(float a, bf16_t& h, bf16_t& l) {
  h = (bf16_t)a;
  l = (bf16_t)(a - (float)h);
}

// async global -> LDS, 16B per lane; lds ptr must be wave-uniform (m104/m108)
__device__ __forceinline__ void gld16(const bf16_t* g, bf16_t* l) {
  __builtin_amdgcn_global_load_lds(
      (const __attribute__((address_space(1))) void*)g,
      (__attribute__((address_space(3))) void*)l, 16, 0, 0);
}

// stage a 128x32 bf16 tile (row stride D_DIM) into unpadded LDS.
// wave w covers segments {2w, 2w+1}; seg s = rows 16s..16s+15.
#define STAGE_TILE128(src, dst)                                               \
  {                                                                           \
    const int seg0 = wave * 2;                                                \
    const int r0 = seg0 * 16 + (lane >> 2);                                   \
    const int c0 = (lane & 3) * 8;                                            \
    gld16((src) + (size_t)r0 * D_DIM + c0, (dst) + seg0 * 512);               \
    gld16((src) + (size_t)(r0 + 16) * D_DIM + c0, (dst) + (seg0 + 1) * 512);  \
  }

// stage a 64x32 bf16 tile: one 16-row segment per wave.
#define STAGE_TILE64(src, dst)                                                \
  {                                                                           \
    const int r0 = wave * 16 + (lane >> 2);                                   \
    const int c0 = (lane & 3) * 8;                                            \
    gld16((src) + (size_t)r0 * D_DIM + c0, (dst) + wave * 512);               \
  }

// ---------------------------------------------------------------------------
// prep: pre-split x and Wq into bf16 hi/lo; pre-round Wk/Wv/Wo to bf16.
// ---------------------------------------------------------------------------
__global__ __launch_bounds__(256) void prep_kernel(
    const float* __restrict__ x,  const float* __restrict__ Wq,
    const float* __restrict__ Wk, const float* __restrict__ Wv,
    const float* __restrict__ Wo,
    bf16_t* __restrict__ xhi, bf16_t* __restrict__ xlo,
    bf16_t* __restrict__ Wqhi, bf16_t* __restrict__ Wqlo,
    bf16_t* __restrict__ Wkb,  bf16_t* __restrict__ Wvb,
    bf16_t* __restrict__ Wob)
{
  const int XV = (M_DIM * D_DIM) / 4;
  const int WV = (D_DIM * D_DIM) / 4;
  int i = blockIdx.x * 256 + threadIdx.x;
  if (i < XV) {
    f32x4 v = ((const f32x4*)x)[i];
    bf16x4 h, l;
    #pragma unroll
    for (int j = 0; j < 4; ++j) { bf16_t hh, ll; split2(v[j], hh, ll); h[j] = hh; l[j] = ll; }
    ((bf16x4*)xhi)[i] = h;
    ((bf16x4*)xlo)[i] = l;
  } else if (i < XV + WV) {
    int j0 = i - XV;
    f32x4 v = ((const f32x4*)Wq)[j0];
    bf16x4 h, l;
    #pragma unroll
    for (int j = 0; j < 4; ++j) { bf16_t hh, ll; split2(v[j], hh, ll); h[j] = hh; l[j] = ll; }
    ((bf16x4*)Wqhi)[j0] = h;
    ((bf16x4*)Wqlo)[j0] = l;
  } else if (i < XV + 2 * WV) {
    int j0 = i - XV - WV;
    f32x4 v = ((const f32x4*)Wk)[j0];
    bf16x4 h;
    #pragma unroll
    for (int j = 0; j < 4; ++j) h[j] = (bf16_t)v[j];
    ((bf16x4*)Wkb)[j0] = h;
  } else if (i < XV + 3 * WV) {
    int j0 = i - XV - 2 * WV;
    f32x4 v = ((const f32x4*)Wv)[j0];
    bf16x4 h;
    #pragma unroll
    for (int j = 0; j < 4; ++j) h[j] = (bf16_t)v[j];
    ((bf16x4*)Wvb)[j0] = h;
  } else {
    int j0 = i - XV - 3 * WV;
    f32x4 v = ((const f32x4*)Wo)[j0];
    bf16x4 h;
    #pragma unroll
    for (int j = 0; j < 4; ++j) h[j] = (bf16_t)v[j];
    ((bf16x4*)Wob)[j0] = h;
  }
}

// ---------------------------------------------------------------------------
// Fused QKV projections — r3 structure (measured best: 62 µs, 3 blocks/CU).
// Prefetch double-buffered staging; z0 split into A/B phases at 48 KB LDS.
// K written per-head [b][h][L][64]; V per-head key-tiled [(b,h)][kb][d][32].
// ---------------------------------------------------------------------------
__global__ __launch_bounds__(256, 3) void gemm_qkv(
    const bf16_t* __restrict__ xhi, const bf16_t* __restrict__ xlo,
    const bf16_t* __restrict__ Wqhi, const bf16_t* __restrict__ Wqlo,
    const bf16_t* __restrict__ Wkb, const bf16_t* __restrict__ Wvb,
    const float* __restrict__ bq, const float* __restrict__ bk, const float* __restrict__ bv,
    bf16_t* __restrict__ Qhi, bf16_t* __restrict__ Khi, bf16_t* __restrict__ VThi,
    float* __restrict__ norms)
{
  const int bx = blockIdx.x;
  const int z  = bx % 3;          // interleaved so each CU gets a z-mix
  const int id = bx / 3;          // 0..255
  const int n0   = (id & 7) * 128;
  const int row0 = (id >> 3) * 128;

  __shared__ __align__(16) bf16_t sm[2][3][4096];   // 48 KB: dbuf x 3 tiles

  const int tid  = threadIdx.x;
  const int lane = tid & 63;
  const int wave = tid >> 6;
  const int wr = wave >> 1, wc = wave & 1;
  const int lm = lane & 15, quad = lane >> 4;

  const f32x4 vzero = {0.f, 0.f, 0.f, 0.f};
  f32x4 acc[4][4];
  #pragma unroll
  for (int mi = 0; mi < 4; ++mi)
    #pragma unroll
    for (int ni = 0; ni < 4; ++ni) acc[mi][ni] = vzero;

  if (z == 0) {
#define STAGE_A(k0, b) do {                                                  \
      STAGE_TILE128(xhi  + (size_t)row0 * D_DIM + (k0), sm[b][0]);           \
      STAGE_TILE128(Wqhi + (size_t)n0   * D_DIM + (k0), sm[b][1]);           \
      STAGE_TILE128(Wqlo + (size_t)n0   * D_DIM + (k0), sm[b][2]);           \
    } while (0)
#define STAGE_B(k0, b) do {                                                  \
      STAGE_TILE128(xlo  + (size_t)row0 * D_DIM + (k0), sm[b][0]);           \
      STAGE_TILE128(Wqhi + (size_t)n0   * D_DIM + (k0), sm[b][1]);           \
    } while (0)

    STAGE_A(0, 0);
    __syncthreads();
    int cur = 0;
    // phase A: acc += xh*Wqh + xh*Wql
    for (int k0 = 0; k0 < D_DIM; k0 += 32) {
      if (k0 + 32 < D_DIM) STAGE_A(k0 + 32, cur ^ 1);
      else                 STAGE_B(0, cur ^ 1);       // bridge into phase B
      bf16x8 af[4], bh0[4], bl0[4];
      #pragma unroll
      for (int mi = 0; mi < 4; ++mi)
        af[mi] = *reinterpret_cast<const bf16x8*>(&sm[cur][0][(wr * 64 + mi * 16 + lm) * 32 + quad * 8]);
      #pragma unroll
      for (int ni = 0; ni < 4; ++ni) {
        bh0[ni] = *reinterpret_cast<const bf16x8*>(&sm[cur][1][(wc * 64 + ni * 16 + lm) * 32 + quad * 8]);
        bl0[ni] = *reinterpret_cast<const bf16x8*>(&sm[cur][2][(wc * 64 + ni * 16 + lm) * 32 + quad * 8]);
      }
      #pragma unroll
      for (int mi = 0; mi < 4; ++mi)
        #pragma unroll
        for (int ni = 0; ni < 4; ++ni) {
          acc[mi][ni] = __builtin_amdgcn_mfma_f32_16x16x32_bf16(af[mi], bh0[ni], acc[mi][ni], 0, 0, 0);
          acc[mi][ni] = __builtin_amdgcn_mfma_f32_16x16x32_bf16(af[mi], bl0[ni], acc[mi][ni], 0, 0, 0);
        }
      __syncthreads();
      cur ^= 1;
    }
    // phase B: acc += xl*Wqh
    for (int k0 = 0; k0 < D_DIM; k0 += 32) {
      if (k0 + 32 < D_DIM) STAGE_B(k0 + 32, cur ^ 1);
      bf16x8 af[4], bh0[4];
      #pragma unroll
      for (int mi = 0; mi < 4; ++mi)
        af[mi] = *reinterpret_cast<const bf16x8*>(&sm[cur][0][(wr * 64 + mi * 16 + lm) * 32 + quad * 8]);
      #pragma unroll
      for (int ni = 0; ni < 4; ++ni)
        bh0[ni] = *reinterpret_cast<const bf16x8*>(&sm[cur][1][(wc * 64 + ni * 16 + lm) * 32 + quad * 8]);
      #pragma unroll
      for (int mi = 0; mi < 4; ++mi)
        #pragma unroll
        for (int ni = 0; ni < 4; ++ni)
          acc[mi][ni] = __builtin_amdgcn_mfma_f32_16x16x32_bf16(af[mi], bh0[ni], acc[mi][ni], 0, 0, 0);
      __syncthreads();
      cur ^= 1;
    }

    float bvv[4];
    #pragma unroll
    for (int ni = 0; ni < 4; ++ni) bvv[ni] = bq[n0 + wc * 64 + ni * 16 + lm];
    #pragma unroll
    for (int mi = 0; mi < 4; ++mi)
      #pragma unroll
      for (int ni = 0; ni < 4; ++ni)
        #pragma unroll
        for (int r = 0; r < 4; ++r) acc[mi][ni][r] += bvv[ni];

    const int h = (n0 + wc * 64) >> 6;
    #pragma unroll
    for (int mi = 0; mi < 4; ++mi)
      #pragma unroll
      for (int r = 0; r < 4; ++r) {
        float s = 0.f;
        #pragma unroll
        for (int ni = 0; ni < 4; ++ni) { float v = acc[mi][ni][r]; s += v * v; }
        s += __shfl_xor(s, 1); s += __shfl_xor(s, 2);
        s += __shfl_xor(s, 4); s += __shfl_xor(s, 8);
        if (lm == 0) {
          int row = row0 + wr * 64 + mi * 16 + quad * 4 + r;
          int bb = row >> 11, ll = row & (L_DIM - 1);
          norms[(bb * H_DIM + h) * L_DIM + ll] = s;
        }
      }

    #pragma unroll
    for (int mi = 0; mi < 4; ++mi)
      #pragma unroll
      for (int r = 0; r < 4; ++r) {
        int row = row0 + wr * 64 + mi * 16 + quad * 4 + r;
        #pragma unroll
        for (int ni = 0; ni < 4; ++ni)
          Qhi[(size_t)row * D_DIM + n0 + wc * 64 + ni * 16 + lm] = (bf16_t)acc[mi][ni][r];
      }
  } else {
    const bf16_t* W = (z == 1) ? Wkb : Wvb;
#define STAGE_L(k0, b) do {                                                  \
      STAGE_TILE128(xhi + (size_t)row0 * D_DIM + (k0), sm[b][0]);            \
      STAGE_TILE128(W   + (size_t)n0   * D_DIM + (k0), sm[b][1]);            \
    } while (0)

    STAGE_L(0, 0);
    __syncthreads();
    int cur = 0;
    for (int k0 = 0; k0 < D_DIM; k0 += 32) {
      if (k0 + 32 < D_DIM) STAGE_L(k0 + 32, cur ^ 1);
      bf16x8 af[4], bfr[4];
      #pragma unroll
      for (int mi = 0; mi < 4; ++mi)
        af[mi] = *reinterpret_cast<const bf16x8*>(&sm[cur][0][(wr * 64 + mi * 16 + lm) * 32 + quad * 8]);
      #pragma unroll
      for (int ni = 0; ni < 4; ++ni)
        bfr[ni] = *reinterpret_cast<const bf16x8*>(&sm[cur][1][(wc * 64 + ni * 16 + lm) * 32 + quad * 8]);
      #pragma unroll
      for (int mi = 0; mi < 4; ++mi)
        #pragma unroll
        for (int ni = 0; ni < 4; ++ni)
          acc[mi][ni] = __builtin_amdgcn_mfma_f32_16x16x32_bf16(af[mi], bfr[ni], acc[mi][ni], 0, 0, 0);
      __syncthreads();
      cur ^= 1;
    }

    const float* bias = (z == 1) ? bk : bv;
    float bvv[4];
    #pragma unroll
    for (int ni = 0; ni < 4; ++ni) bvv[ni] = bias[n0 + wc * 64 + ni * 16 + lm];
    #pragma unroll
    for (int mi = 0; mi < 4; ++mi)
      #pragma unroll
      for (int ni = 0; ni < 4; ++ni)
        #pragma unroll
        for (int r = 0; r < 4; ++r) acc[mi][ni][r] += bvv[ni];

    const int hh = (n0 + wc * 64) >> 6;   // head 0..15
    if (z == 1) {
      // Khead[b][h][l][64]
      #pragma unroll
      for (int mi = 0; mi < 4; ++mi)
        #pragma unroll
        for (int r = 0; r < 4; ++r) {
          int row = row0 + wr * 64 + mi * 16 + quad * 4 + r;
          int bb = row >> 11, ll = row & (L_DIM - 1);
          size_t base = (size_t)(bb * H_DIM + hh) * HSZ + (size_t)ll * 64;
          #pragma unroll
          for (int ni = 0; ni < 4; ++ni)
            Khi[base + ni * 16 + lm] = (bf16_t)acc[mi][ni][r];
        }
    } else {
      // V key-tiled: [(b,h)][kb=l/32][d][32]
      #pragma unroll
      for (int mi = 0; mi < 4; ++mi) {
        int rbase = row0 + wr * 64 + mi * 16 + quad * 4;
        int bb = rbase >> 11, l0 = rbase & (L_DIM - 1);
        int kbv = l0 >> 5, kin = l0 & 31;
        size_t hb = (size_t)(bb * H_DIM + hh) * HSZ;
        #pragma unroll
        for (int ni = 0; ni < 4; ++ni) {
          int d = ni * 16 + lm;
          bf16x4 wv;
          #pragma unroll
          for (int r = 0; r < 4; ++r) wv[r] = (bf16_t)acc[mi][ni][r];
          *reinterpret_cast<bf16x4*>(&VThi[hb + (size_t)(kbv * 64 + d) * 32 + kin]) = wv;
        }
      }
    }
  }
}

// ---------------------------------------------------------------------------
// Output projection: 64x128 tiles, grid (8,64) = 2 blocks/CU, prefetch dbuf.
// ---------------------------------------------------------------------------
__global__ __launch_bounds__(256) void gemm_out(
    const bf16_t* __restrict__ Ahi, const bf16_t* __restrict__ Wob,
    const float* __restrict__ bias, float* __restrict__ C)
{
  const int n0   = blockIdx.x * 128;
  const int row0 = blockIdx.y * 64;

  __shared__ __align__(16) bf16_t sm[2][6144];   // 24 KB: dbuf x (A64 + B128)

  const int tid  = threadIdx.x;
  const int lane = tid & 63;
  const int wave = tid >> 6;
  const int wr = wave >> 1, wc = wave & 1;
  const int lm = lane & 15, quad = lane >> 4;

  const f32x4 vzero = {0.f, 0.f, 0.f, 0.f};
  f32x4 acc[2][4];
  #pragma unroll
  for (int mi = 0; mi < 2; ++mi)
    #pragma unroll
    for (int ni = 0; ni < 4; ++ni) acc[mi][ni] = vzero;

#define STAGE_O(k0, b) do {                                                  \
    STAGE_TILE64(Ahi + (size_t)row0 * D_DIM + (k0), sm[b]);                  \
    STAGE_TILE128(Wob + (size_t)n0 * D_DIM + (k0), sm[b] + 2048);            \
  } while (0)

  STAGE_O(0, 0);
  __syncthreads();
  int cur = 0;
  for (int k0 = 0; k0 < D_DIM; k0 += 32) {
    if (k0 + 32 < D_DIM) STAGE_O(k0 + 32, cur ^ 1);
    bf16x8 af[2], bfr[4];
    #pragma unroll
    for (int mi = 0; mi < 2; ++mi)
      af[mi] = *reinterpret_cast<const bf16x8*>(&sm[cur][(wr * 32 + mi * 16 + lm) * 32 + quad * 8]);
    #pragma unroll
    for (int ni = 0; ni < 4; ++ni)
      bfr[ni] = *reinterpret_cast<const bf16x8*>(&sm[cur][2048 + (wc * 64 + ni * 16 + lm) * 32 + quad * 8]);
    #pragma unroll
    for (int mi = 0; mi < 2; ++mi)
      #pragma unroll
      for (int ni = 0; ni < 4; ++ni)
        acc[mi][ni] = __builtin_amdgcn_mfma_f32_16x16x32_bf16(af[mi], bfr[ni], acc[mi][ni], 0, 0, 0);
    __syncthreads();
    cur ^= 1;
  }

  float bvv[4];
  #pragma unroll
  for (int ni = 0; ni < 4; ++ni) bvv[ni] = bias[n0 + wc * 64 + ni * 16 + lm];
  #pragma unroll
  for (int mi = 0; mi < 2; ++mi)
    #pragma unroll
    for (int r = 0; r < 4; ++r) {
      int row = row0 + wr * 32 + mi * 16 + quad * 4 + r;
      #pragma unroll
      for (int ni = 0; ni < 4; ++ni)
        C[(size_t)row * D_DIM + n0 + wc * 64 + ni * 16 + lm] = acc[mi][ni][r] + bvv[ni];
    }
}

// ---------------------------------------------------------------------------
// Exact top-409 per (b,h) via 4-pass 8-bit radix select on f32 bits
// (norms >= 0 so uint ordering == float ordering), then ballot-prefix
// write-out. Set matches lax.top_k exactly: all keys > T, plus the
// (KTOP - count_gt) smallest-index keys == T.
// Replaces the 66-barrier-stage bitonic sort (latency-bound, 32 blocks).
// ---------------------------------------------------------------------------
__global__ __launch_bounds__(1024) void topk_kernel(
    const float* __restrict__ norms, int* __restrict__ sel)
{
  const int bh = blockIdx.x;
  const int t  = threadIdx.x;
  const int w  = t >> 6;            // wave 0..15
  const int lane = t & 63;

  __shared__ int bins[256];
  __shared__ unsigned int sh_pfx;
  __shared__ int cnt0[16], cnt1[16], ecnt0[16], ecnt1[16];

  // two keys per thread, index order: k0 -> index t, k1 -> index t+1024
  const unsigned int k0 = __float_as_uint(norms[bh * L_DIM + t]);
  const unsigned int k1 = __float_as_uint(norms[bh * L_DIM + t + 1024]);

  // ---- find T = KTOP-th largest key (exact, 4 passes of 8 bits) ----
  unsigned int pfx = 0;   // high bits fixed so far (in low positions)
  int r = KTOP;           // rank remaining among qualifying keys
  #pragma unroll
  for (int p = 0; p < 4; ++p) {
    const int sh = 24 - 8 * p;
    if (t < 256) bins[t] = 0;
    __syncthreads();
    const bool q0 = (p == 0) || ((k0 >> (sh + 8)) == pfx);
    const bool q1 = (p == 0) || ((k1 >> (sh + 8)) == pfx);
    if (q0) atomicAdd(&bins[(k0 >> sh) & 255], 1);
    if (q1) atomicAdd(&bins[(k1 >> sh) & 255], 1);
    __syncthreads();
    if (t == 0) {
      int cum = 0, B = 0;
      for (int v = 255; v >= 0; --v) {
        int c = bins[v];
        if (cum + c >= r) { B = v; r -= cum; break; }
        cum += c;
      }
      sh_pfx = (pfx << 8) | (unsigned int)B;
      bins[0] = r;          // reuse as broadcast slot (post-barrier read)
    }
    __syncthreads();
    pfx = sh_pfx;
    r = bins[0];
    __syncthreads();
  }
  const unsigned int T = pfx;

  // ---- selection write-out ----
  const bool gt0 = (k0 > T), gt1 = (k1 > T);
  const bool eq0 = (k0 == T), eq1 = (k1 == T);
  const unsigned long long mlt = (lane == 63) ? 0x7fffffffffffffffull
                                              : ((1ull << lane) - 1ull);
  const unsigned long long bg0 = __ballot(gt0);
  const unsigned long long bg1 = __ballot(gt1);
  const unsigned long long be0 = __ballot(eq0);
  const unsigned long long be1 = __ballot(eq1);
  if (lane == 0) {
    cnt0[w]  = __popcll(bg0);
    cnt1[w]  = __popcll(bg1);
    ecnt0[w] = __popcll(be0);
    ecnt1[w] = __popcll(be1);
  }
  __syncthreads();
  int og0 = 0, og1 = 0, oe0 = 0, oe1 = 0;
  int tg0 = 0, tg1 = 0, te0 = 0;
  #pragma unroll
  for (int i = 0; i < 16; ++i) {
    if (i < w) { og0 += cnt0[i]; og1 += cnt1[i]; oe0 += ecnt0[i]; oe1 += ecnt1[i]; }
    tg0 += cnt0[i]; tg1 += cnt1[i]; te0 += ecnt0[i];
  }
  const int G = tg0 + tg1;          // total keys > T (G < KTOP)
  const int take = KTOP - G;        // ties to take, earliest index first
  const int base = bh * SLOTS;

  if (gt0) sel[base + og0 + __popcll(bg0 & mlt)] = t;
  if (gt1) sel[base + tg0 + og1 + __popcll(bg1 & mlt)] = t + 1024;
  if (eq0) {
    int rk = oe0 + __popcll(be0 & mlt);
    if (rk < take) sel[base + G + rk] = t;
  }
  if (eq1) {
    int rk = te0 + oe1 + __popcll(be1 & mlt);
    if (rk < take) sel[base + G + rk] = t + 1024;
  }
  if (t < SLOTS - KTOP) sel[base + KTOP + t] = -1;
}

// ---------------------------------------------------------------------------
// K-split flash attention. K per-head [b][h][L][64]; V key-tiled
// [(b,h)][kb][d][32]. XCD-affinity block swizzle; 2x-unrolled inner loop
// with double-buffered P.
// ---------------------------------------------------------------------------
__global__ __launch_bounds__(256) void attn_kernel(
    const bf16_t* __restrict__ Qhi,
    const bf16_t* __restrict__ Khi,
    const bf16_t* __restrict__ VThi,
    const int* __restrict__ sel,
    float* __restrict__ Ol, bf16_t* __restrict__ Oo)
{
  const int bx = blockIdx.x;
  const int xl = bx & 7;          // XCD id under default round-robin
  const int rest = bx >> 3;       // 0..223
  const int qc = rest % 7;
  const int gh = rest / 7;        // 0..31
  const int g  = gh * 8 + xl;     // K/V-chunk group 0..255
  const int bh = g & 31;
  const int ks = g >> 5;
  const int b = bh >> 4, h = bh & 15;
  const int wave = threadIdx.x >> 6;
  const int lane = threadIdx.x & 63;
  const int lm = lane & 15, quad = lane >> 4;

  __shared__ __align__(16) bf16_t sPh[2][4][16][40];

  const int qbase = qc * 64 + wave * 16;
  const int qi = sel[bh * SLOTS + qbase + lm];
  const size_t qo = ((size_t)(b * L_DIM + (qi >= 0 ? qi : 0))) * D_DIM + h * 64;
  const bf16x8 qa0 = *reinterpret_cast<const bf16x8*>(&Qhi[qo + quad * 8]);
  const bf16x8 qa1 = *reinterpret_cast<const bf16x8*>(&Qhi[qo + 32 + quad * 8]);

  const f32x4 vzero = {0.f, 0.f, 0.f, 0.f};
  float l_l[4] = {0.f, 0.f, 0.f, 0.f};
  f32x4 o[4];
  #pragma unroll
  for (int ni = 0; ni < 4; ++ni) o[ni] = vzero;

  const float scale = 0.125f;
  const size_t khead = (size_t)(b * H_DIM + h) * HSZ;
  const int key0 = ks * KCHUNK;

  // inner name 'kof' differs from the caller's loop var (r2 self-shadow UB)
#define ATTN_STEP(KT, PB)                                                     \
  {                                                                           \
    const int kof = (KT);                                                     \
    size_t kr0 = khead + (size_t)(key0 + kof + lm) * 64;                      \
    size_t kr1 = khead + (size_t)(key0 + kof + 16 + lm) * 64;                 \
    bf16x8 kb0 = *reinterpret_cast<const bf16x8*>(&Khi[kr0 + quad * 8]);      \
    bf16x8 kb1 = *reinterpret_cast<const bf16x8*>(&Khi[kr0 + 32 + quad * 8]); \
    bf16x8 kb2 = *reinterpret_cast<const bf16x8*>(&Khi[kr1 + quad * 8]);      \
    bf16x8 kb3 = *reinterpret_cast<const bf16x8*>(&Khi[kr1 + 32 + quad * 8]); \
    const int kbv = (key0 + kof) >> 5;                                        \
    bf16x8 vbh[4];                                                            \
    _Pragma("unroll")                                                         \
    for (int ni = 0; ni < 4; ++ni) {                                          \
      size_t vo = khead + (size_t)(kbv * 64 + ni * 16 + lm) * 32 + quad * 8;  \
      vbh[ni] = *reinterpret_cast<const bf16x8*>(&VThi[vo]);                  \
    }                                                                         \
    f32x4 s0 = vzero, s1 = vzero;                                             \
    s0 = __builtin_amdgcn_mfma_f32_16x16x32_bf16(qa0, kb0, s0, 0, 0, 0);      \
    s0 = __builtin_amdgcn_mfma_f32_16x16x32_bf16(qa1, kb1, s0, 0, 0, 0);      \
    s1 = __builtin_amdgcn_mfma_f32_16x16x32_bf16(qa0, kb2, s1, 0, 0, 0);      \
    s1 = __builtin_amdgcn_mfma_f32_16x16x32_bf16(qa1, kb3, s1, 0, 0, 0);      \
    _Pragma("unroll")                                                         \
    for (int r = 0; r < 4; ++r) {                                             \
      float p0 = __expf(s0[r] * scale);                                       \
      float p1 = __expf(s1[r] * scale);                                       \
      l_l[r] += p0 + p1;                                                      \
      sPh[PB][wave][quad * 4 + r][lm]      = (bf16_t)p0;                      \
      sPh[PB][wave][quad * 4 + r][16 + lm] = (bf16_t)p1;                      \
    }                                                                         \
    bf16x8 pah = *reinterpret_cast<const bf16x8*>(&sPh[PB][wave][lm][quad * 8]); \
    _Pragma("unroll")                                                         \
    for (int ni = 0; ni < 4; ++ni)                                            \
      o[ni] = __builtin_amdgcn_mfma_f32_16x16x32_bf16(pah, vbh[ni], o[ni], 0, 0, 0); \
  }

  for (int kt = 0; kt < KCHUNK; kt += 64) {
    ATTN_STEP(kt, 0);
    ATTN_STEP(kt + 32, 1);
  }

  #pragma unroll
  for (int r = 0; r < 4; ++r) {
    l_l[r] += __shfl_xor(l_l[r], 1);
    l_l[r] += __shfl_xor(l_l[r], 2);
    l_l[r] += __shfl_xor(l_l[r], 4);
    l_l[r] += __shfl_xor(l_l[r], 8);
  }

  #pragma unroll
  for (int r = 0; r < 4; ++r) {
    int slot = qbase + quad * 4 + r;
    int s2 = sel[bh * SLOTS + slot];
    if (s2 >= 0) {
      size_t gs = (size_t)(bh * SLOTS + slot) * KSPLIT + ks;
      if (lm == 0) Ol[gs] = l_l[r];
      #pragma unroll
      for (int ni = 0; ni < 4; ++ni)
        Oo[gs * 64 + ni * 16 + lm] = (bf16_t)o[ni][r];
    }
  }
}

// ---------------------------------------------------------------------------
// Combine ksplit partials -> AO (selected rows; meanfill covered the rest).
// ---------------------------------------------------------------------------
__global__ __launch_bounds__(256) void combine_kernel(
    const float* __restrict__ Ol, const bf16_t* __restrict__ Oo,
    const int* __restrict__ sel, bf16_t* __restrict__ AOhi)
{
  const int bh = blockIdx.x;
  const int b = bh >> 4, h = bh & 15;
  const int chunk = blockIdx.y;
  const int tid = threadIdx.x;
  const int dim = tid & 63;
  const int sl  = tid >> 6;
  #pragma unroll
  for (int p = 0; p < 4; ++p) {
    int slot = chunk * 16 + p * 4 + sl;
    int qi = sel[bh * SLOTS + slot];
    if (qi < 0) continue;
    size_t gs = (size_t)(bh * SLOTS + slot) * KSPLIT;
    float L = 0.f, ov = 0.f;
    #pragma unroll
    for (int s = 0; s < KSPLIT; ++s) {
      L  += Ol[gs + s];
      ov += (float)Oo[(gs + s) * 64 + dim];
    }
    AOhi[((size_t)(b * L_DIM + qi)) * D_DIM + h * 64 + dim] = (bf16_t)(ov / L);
  }
}

// ---------------------------------------------------------------------------
// mean(V) to EVERY AO row; combine overwrites selected rows.
// V is key-tiled: [(b,h)][kb][d][32].
// ---------------------------------------------------------------------------
__global__ __launch_bounds__(256) void meanfill_kernel(
    const bf16_t* __restrict__ VThi, bf16_t* __restrict__ AOhi)
{
  const int bh = blockIdx.x;
  const int b = bh >> 4, h = bh & 15;
  const int t = threadIdx.x;
  __shared__ __align__(16) bf16_t smh[64];
  {
    const int hd = t >> 2, part = t & 3;
    size_t hbase = (size_t)(b * H_DIM + h) * HSZ;
    float s = 0.f;
    for (int kb = part * 16; kb < part * 16 + 16; ++kb) {
      size_t a = hbase + (size_t)(kb * 64 + hd) * 32;
      bf16x8 v0 = *reinterpret_cast<const bf16x8*>(&VThi[a]);
      bf16x8 v1 = *reinterpret_cast<const bf16x8*>(&VThi[a + 8]);
      bf16x8 v2 = *reinterpret_cast<const bf16x8*>(&VThi[a + 16]);
      bf16x8 v3 = *reinterpret_cast<const bf16x8*>(&VThi[a + 24]);
      #pragma unroll
      for (int j = 0; j < 8; ++j)
        s += (float)v0[j] + (float)v1[j] + (float)v2[j] + (float)v3[j];
    }
    s += __shfl_xor(s, 1);
    s += __shfl_xor(s, 2);
    if (part == 0) smh[hd] = (bf16_t)(s * (1.0f / (float)L_DIM));
  }
  __syncthreads();
  const int lbase = blockIdx.y * 256;
  for (int i = t; i < 256 * 64; i += 256) {
    int l = lbase + (i >> 6), hd = i & 63;
    AOhi[((size_t)(b * L_DIM + l)) * D_DIM + h * 64 + hd] = smh[hd];
  }
}

// ---------------------------------------------------------------------------
extern "C" void kernel_launch(void* const* d_in, const int* in_sizes, int n_in,
                              void* d_out, int out_size, void* d_ws, size_t ws_size,
                              hipStream_t stream) {
  const float* x  = (const float*)d_in[0];
  const float* Wq = (const float*)d_in[1];
  const float* bq = (const float*)d_in[2];
  const float* Wk = (const float*)d_in[3];
  const float* bk = (const float*)d_in[4];
  const float* Wv = (const float*)d_in[5];
  const float* bv = (const float*)d_in[6];
  const float* Wo = (const float*)d_in[7];
  const float* bo = (const float*)d_in[8];
  float* out = (float*)d_out;

  // ws layout (~43 MB):
  //  [0,8)    Qhi  (aliased as AOhi after attn)
  //  [8,16)   VThi (key-tiled per-head layout)
  //  [16,24)  xhi  -+ dead after gemm_qkv; [16,32) reused for Oo (bf16, 14.7MB)
  //  [24,32)  xlo  -+
  //  [32,34)  Wqhi  [34,36) Wqlo  [36,38) Wkb  [38,40) Wvb  [40,42) Wob
  //  [42,..)  norms (256 KB), sel (57 KB), Ol (458 KB)
  // Khi (per-head layout) lives in d_out (8 of 16 MB) — dead until gemm_out.
  const size_t MB = 1u << 20;
  char* ws = (char*)d_ws;
  bf16_t* Qhi  = (bf16_t*)(ws);
  bf16_t* VThi = (bf16_t*)(ws + 8 * MB);
  bf16_t* xhi  = (bf16_t*)(ws + 16 * MB);
  bf16_t* xlo  = (bf16_t*)(ws + 24 * MB);
  bf16_t* Oo   = (bf16_t*)(ws + 16 * MB);         // aliases xhi/xlo
  bf16_t* Wqhi = (bf16_t*)(ws + 32 * MB);
  bf16_t* Wqlo = (bf16_t*)(ws + 34 * MB);
  bf16_t* Wkb  = (bf16_t*)(ws + 36 * MB);
  bf16_t* Wvb  = (bf16_t*)(ws + 38 * MB);
  bf16_t* Wob  = (bf16_t*)(ws + 40 * MB);
  float*  norms = (float*)(ws + 42 * MB);
  int*    sel   = (int*)(ws + 42 * MB + (256u << 10));
  float*  Ol    = (float*)(ws + 42 * MB + (320u << 10));
  bf16_t* AOhi = Qhi;
  bf16_t* Khi = (bf16_t*)d_out;

  dim3 blk(256);
  prep_kernel<<<dim3(8192), blk, 0, stream>>>(x, Wq, Wk, Wv, Wo,
                                              xhi, xlo, Wqhi, Wqlo, Wkb, Wvb, Wob);
  gemm_qkv<<<dim3(768), blk, 0, stream>>>(xhi, xlo, Wqhi, Wqlo, Wkb, Wvb,
                                          bq, bk, bv, Qhi, Khi, VThi, norms);
  topk_kernel<<<dim3(32), dim3(1024), 0, stream>>>(norms, sel);
  attn_kernel<<<dim3(32 * 7 * KSPLIT), blk, 0, stream>>>(Qhi, Khi, VThi, sel, Ol, Oo);
  meanfill_kernel<<<dim3(32, 8), blk, 0, stream>>>(VThi, AOhi);
  combine_kernel<<<dim3(32, 28), blk, 0, stream>>>(Ol, Oo, sel, AOhi);
  gemm_out<<<dim3(8, 64), blk, 0, stream>>>(AOhi, Wob, bo, out);
}